// Round 6
// baseline (136.922 us; speedup 1.0000x reference)
//
#include <hip/hip_runtime.h>

#define HID 50
#define TSTEPS 256
#define SPB 8               // samples per block (grid = 512 -> 2 blocks/CU)
#define NW 7                // waves per block; 2 M-tiles each: 224 rows >= 200
#define THREADS (NW * 64)
#define XSTRIDE 257         // floats per sample in x_lds

#if __has_builtin(__builtin_amdgcn_exp2f)
#define EXP2(x) __builtin_amdgcn_exp2f(x)
#else
#define EXP2(x) exp2f(x)
#endif
#define L2E 1.44269504088896340736f

typedef __attribute__((ext_vector_type(8))) _Float16 half8;
typedef __attribute__((ext_vector_type(4))) float f32x4;

static __device__ __forceinline__ f32x4 MF16(half8 a, half8 b, f32x4 c) {
    return __builtin_amdgcn_mfma_f32_16x16x32_f16(a, b, c, 0, 0, 0);
}
// 1/(1 + 2^a)
static __device__ __forceinline__ float sig2(float a) {
    return __builtin_amdgcn_rcpf(1.0f + EXP2(a));
}
static __device__ __forceinline__ float fast_tanh(float x) {
    return 1.0f - 2.0f * sig2(2.0f * L2E * x);
}

__global__ __launch_bounds__(THREADS, 4) void hybrid_lstm_fp16b(
    const float* __restrict__ x,      // [B,256,1]
    const float* __restrict__ W_ih,   // [200,1]
    const float* __restrict__ W_hh,   // [200,50]
    const float* __restrict__ b_ih,   // [200]
    const float* __restrict__ b_hh,   // [200]
    const float* __restrict__ Wp,     // [4,50]
    const float* __restrict__ bp,     // [4]
    const float* __restrict__ qw,     // [2,4,3]
    const float* __restrict__ Wo,     // [1,4]
    const float* __restrict__ bo,     // [1]
    float* __restrict__ out)          // [B,1]
{
    __shared__ __align__(16) float x_lds[SPB * XSTRIDE];
    // [buf][chunk(2)][sample(16)][slot(32)] fp16; slot == unit (identity map).
    // B-read: lane reads 8 contiguous slots (g2*8..+7) of sample qs in each
    // chunk -> 16B/lane, 64 distinct 16B segments -> conflict-free.
    // Samples 8..15 are never written and stay zero.
    __shared__ __align__(16) _Float16 h_tab[2][1024];

    const int tid  = threadIdx.x;
    const int wid  = tid >> 6;        // 0..6
    const int lane = tid & 63;
    const int qs   = lane & 15;       // MFMA column / A-row-within-tile
    const int g2   = lane >> 4;       // K-group / C-row-group

    // ---------- prologue: zero h tables, stage x ----------
    {
        unsigned* hz = (unsigned*)&h_tab[0][0];
        for (int i = tid; i < 1024; i += THREADS) hz[i] = 0u;
        const float* xg = x + (size_t)blockIdx.x * SPB * TSTEPS;
        for (int i = tid; i < SPB * TSTEPS; i += THREADS)
            x_lds[(i >> 8) * XSTRIDE + (i & 255)] = xg[i];
    }

    // ---------- A fragments (gate-scaled fp16), 2 tiles per wave ----------
    // tile ti: rows 16*(2*wid+ti); A-row-within-tile = qs -> unit uA = 8*wid+4*ti+(qs>>2),
    // gate q = qs&3 (i,f,g,o). K element (kh,r): slot = kh*32 + g2*8 + r = unit (identity).
    // gate scale: i,f,o rows * -log2e ; g row * 2*log2e (exp2-native gates)
    half8 Ah[2][2];
    {
        const int q    = qs & 3;
        const float sc = (q == 2) ? 2.0f * L2E : -L2E;
#pragma unroll
        for (int ti = 0; ti < 2; ++ti) {
            const int uA  = 8 * wid + 4 * ti + (qs >> 2);
            const bool vr = (uA < HID);
            const int orow = q * HID + (vr ? uA : 0);
#pragma unroll
            for (int kh = 0; kh < 2; ++kh) {
#pragma unroll
                for (int r = 0; r < 8; ++r) {
                    const int un = kh * 32 + g2 * 8 + r;
                    float v = 0.0f;
                    if (vr && un < HID) v = sc * W_hh[orow * HID + un];
                    Ah[ti][kh][r] = (_Float16)v;
                }
            }
        }
    }

    // acc-init consts: acc_ti[reg] = gate 'reg' of unit uC = 8*wid + 4*ti + g2
    float wihc[2][4], bsumc[2][4];
#pragma unroll
    for (int ti = 0; ti < 2; ++ti) {
        const int uC  = 8 * wid + 4 * ti + g2;
        const bool cv = (uC < HID);
#pragma unroll
        for (int reg = 0; reg < 4; ++reg) {
            const float sc = (reg == 2) ? 2.0f * L2E : -L2E;
            const int orow = reg * HID + (cv ? uC : 0);
            wihc[ti][reg]  = sc * W_ih[orow];
            bsumc[ti][reg] = sc * (b_ih[orow] + b_hh[orow]);
        }
    }

    // post-repack element owned by this lane: sample s_l, unit u_l
    const int s_l = qs & 7;
    const int u_l = 8 * wid + 4 * (qs >> 3) + g2;
    const bool wv = (u_l < HID);
    _Float16* const wp0 = &h_tab[0][(u_l >> 5) * 512 + s_l * 32 + (u_l & 31)];

    __syncthreads();

    float cst = 0.0f;
    half8 bh0, bh1;
    auto loadB = [&](int buf) {
        const _Float16* bp_ = &h_tab[buf][qs * 32 + g2 * 8];
        bh0 = *(const half8*)(bp_);
        bh1 = *(const half8*)(bp_ + 512);
    };

    loadB(1);                                  // h(-1) = 0 from zeroed buf1
    float xt = x_lds[s_l * XSTRIDE];           // t = 0
    const bool hi8 = (qs >= 8);

#pragma unroll 2
    for (int t = 0; t < TSTEPS; ++t) {
        // acc init carries exact fp32 (scaled) bias + W_ih*x_t
        f32x4 acc0, acc1;
#pragma unroll
        for (int reg = 0; reg < 4; ++reg) {
            acc0[reg] = fmaf(wihc[0][reg], xt, bsumc[0][reg]);
            acc1[reg] = fmaf(wihc[1][reg], xt, bsumc[1][reg]);
        }
        acc0 = MF16(Ah[0][0], bh0, acc0);
        acc1 = MF16(Ah[1][0], bh0, acc1);
        acc0 = MF16(Ah[0][1], bh1, acc0);
        acc1 = MF16(Ah[1][1], bh1, acc1);

        // repack: lane qs>=8 takes acc1 of lane qs-8 -> 64 lanes = 8 samples x 8 units
        const float r0 = __shfl_xor(acc1[0], 8);
        const float r1 = __shfl_xor(acc1[1], 8);
        const float r2 = __shfl_xor(acc1[2], 8);
        const float r3 = __shfl_xor(acc1[3], 8);
        const float a0 = hi8 ? r0 : acc0[0];
        const float a1 = hi8 ? r1 : acc0[1];
        const float a2 = hi8 ? r2 : acc0[2];
        const float a3 = hi8 ? r3 : acc0[3];

        // a0,a1,a3 = -log2e*pre(i,f,o); a2 = 2log2e*pre(g)
        const float ig = sig2(a0);
        const float fg = sig2(a1);
        const float gg = 1.0f - 2.0f * sig2(a2);
        const float og = sig2(a3);
        cst = fmaf(fg, cst, ig * gg);
        const float h = og * fast_tanh(cst);

        const float xn = x_lds[s_l * XSTRIDE + t + 1];  // prefetch (pad slot at t=255)
        if (wv) wp0[(t & 1) * 1024] = (_Float16)h;
        __syncthreads();
        loadB(t & 1);                                   // h(t) for next step
        xt = xn;
    }

    // ---------- epilogue: angles + 4-qubit circuit, 2 samples per wave (waves 0-3) ----------
    if (wid < 4 && lane < 32) {
        const int sm  = 2 * wid + (lane >> 4);   // 0..7
        const int ql  = lane & 15;
        const int grp = lane & 48;

        const _Float16* t1 = &h_tab[1][0];   // h(255) lives in buf1
        float ang0 = bp[0], ang1 = bp[1], ang2 = bp[2], ang3 = bp[3];
#pragma unroll
        for (int k = 0; k < HID; ++k) {
            const int idx = (k >> 5) * 512 + sm * 32 + (k & 31);
            const float hk = (float)t1[idx];
            ang0 = fmaf(Wp[0 * HID + k], hk, ang0);
            ang1 = fmaf(Wp[1 * HID + k], hk, ang1);
            ang2 = fmaf(Wp[2 * HID + k], hk, ang2);
            ang3 = fmaf(Wp[3 * HID + k], hk, ang3);
        }
        float ang[4];
        ang[0] = fast_tanh(ang0) * 1.57079632679489662f;
        ang[1] = fast_tanh(ang1) * 1.57079632679489662f;
        ang[2] = fast_tanh(ang2) * 1.57079632679489662f;
        ang[3] = fast_tanh(ang3) * 1.57079632679489662f;

        float ar = (ql == 0) ? 1.0f : 0.0f;
        float ai = 0.0f;

        // RX embedding
#pragma unroll
        for (int wq = 0; wq < 4; ++wq) {
            const int mask = 8 >> wq;
            float s_, c_;
            __sincosf(0.5f * ang[wq], &s_, &c_);
            const float pr = __shfl_xor(ar, mask);
            const float pi = __shfl_xor(ai, mask);
            const float nr = c_ * ar + s_ * pi;
            const float ni = c_ * ai - s_ * pr;
            ar = nr; ai = ni;
        }
        // StronglyEntanglingLayers
#pragma unroll
        for (int l = 0; l < 2; ++l) {
#pragma unroll
            for (int wq = 0; wq < 4; ++wq) {
                const float phi = qw[(l * 4 + wq) * 3 + 0];
                const float th  = qw[(l * 4 + wq) * 3 + 1];
                const float om  = qw[(l * 4 + wq) * 3 + 2];
                float st_, ct_, sa, ca, sb, cb;
                __sincosf(0.5f * th, &st_, &ct_);
                __sincosf(0.5f * (phi + om), &sa, &ca);
                __sincosf(0.5f * (phi - om), &sb, &cb);
                const int mask = 8 >> wq;
                const bool bit = (ql & mask) != 0;
                const float dr  = ca * ct_;
                const float di  = (bit ? sa : -sa) * ct_;
                const float orr = (bit ? cb : -cb) * st_;
                const float oi  = -sb * st_;
                const float pr = __shfl_xor(ar, mask);
                const float pi = __shfl_xor(ai, mask);
                const float nr = dr * ar - di * ai + orr * pr - oi * pi;
                const float ni = dr * ai + di * ar + orr * pi + oi * pr;
                ar = nr; ai = ni;
            }
            const int r = (l % 3) + 1;
#pragma unroll
            for (int wq = 0; wq < 4; ++wq) {
                const int mc  = 8 >> wq;
                const int mt  = 8 >> ((wq + r) % 4);
                const int src = (ql & mc) ? (ql ^ mt) : ql;
                ar = __shfl(ar, grp | src);
                ai = __shfl(ai, grp | src);
            }
        }
        const float prob = ar * ar + ai * ai;
        float coeff = 0.0f;
#pragma unroll
        for (int wq = 0; wq < 4; ++wq) {
            const float sgn = (ql & (8 >> wq)) ? -1.0f : 1.0f;
            coeff = fmaf(sgn, Wo[wq], coeff);
        }
        float v = prob * coeff;
        v += __shfl_xor(v, 1);
        v += __shfl_xor(v, 2);
        v += __shfl_xor(v, 4);
        v += __shfl_xor(v, 8);
        if (ql == 0) out[blockIdx.x * SPB + sm] = v + bo[0];
    }
}

extern "C" void kernel_launch(void* const* d_in, const int* in_sizes, int n_in,
                              void* d_out, int out_size, void* d_ws, size_t ws_size,
                              hipStream_t stream) {
    const float* x    = (const float*)d_in[0];
    const float* W_ih = (const float*)d_in[1];
    const float* W_hh = (const float*)d_in[2];
    const float* b_ih = (const float*)d_in[3];
    const float* b_hh = (const float*)d_in[4];
    const float* Wp   = (const float*)d_in[5];
    const float* bp   = (const float*)d_in[6];
    const float* qw   = (const float*)d_in[7];
    const float* Wo   = (const float*)d_in[8];
    const float* bo   = (const float*)d_in[9];
    float* out = (float*)d_out;

    const int B = in_sizes[0] / TSTEPS;
    hybrid_lstm_fp16b<<<B / SPB, THREADS, 0, stream>>>(x, W_ih, W_hh, b_ih, b_hh,
                                                       Wp, bp, qw, Wo, bo, out);
}

// Round 7
// 111.414 us; speedup vs baseline: 1.2289x; 1.2289x over previous
//
#include <hip/hip_runtime.h>

#define HID 50
#define TSTEPS 256
#define SPB 16              // samples per block (MFMA N), grid = 256
#define NW 7                // waves per block; 2 M-tiles each sharing B-reads: 224 rows >= 200
#define THREADS (NW * 64)
#define XSTRIDE 260         // floats per sample in x_lds (16B-aligned rows, bank-spread)

#if __has_builtin(__builtin_amdgcn_exp2f)
#define EXP2(x) __builtin_amdgcn_exp2f(x)
#else
#define EXP2(x) exp2f(x)
#endif
#define L2E 1.44269504088896340736f

typedef __attribute__((ext_vector_type(8))) _Float16 half8;
typedef __attribute__((ext_vector_type(4))) float f32x4;

static __device__ __forceinline__ f32x4 MF16(half8 a, half8 b, f32x4 c) {
    return __builtin_amdgcn_mfma_f32_16x16x32_f16(a, b, c, 0, 0, 0);
}
// 1/(1 + 2^a)
static __device__ __forceinline__ float sig2(float a) {
    return __builtin_amdgcn_rcpf(1.0f + EXP2(a));
}
static __device__ __forceinline__ float fast_tanh(float x) {
    return 1.0f - 2.0f * sig2(2.0f * L2E * x);
}

// slot permutation (verified conflict-clean in R5):
//   s(u) = 8*(u>>3) + 2*(u&3) + ((u>>2)&1)
//   inverse: un(s) = 8*(s>>3) + 4*(s&1) + ((s>>1)&3)
static __device__ __forceinline__ int slot_of_unit(int u) {
    return 8 * (u >> 3) + 2 * (u & 3) + ((u >> 2) & 1);
}

__global__ __launch_bounds__(THREADS, 2) void hybrid_lstm_2t(
    const float* __restrict__ x,      // [B,256,1]
    const float* __restrict__ W_ih,   // [200,1]
    const float* __restrict__ W_hh,   // [200,50]
    const float* __restrict__ b_ih,   // [200]
    const float* __restrict__ b_hh,   // [200]
    const float* __restrict__ Wp,     // [4,50]
    const float* __restrict__ bp,     // [4]
    const float* __restrict__ qw,     // [2,4,3]
    const float* __restrict__ Wo,     // [1,4]
    const float* __restrict__ bo,     // [1]
    float* __restrict__ out)          // [B,1]
{
    __shared__ __align__(16) float x_lds[SPB * XSTRIDE];
    // [buf][chunk-table(2) x 512 fp16]; entry(s,qs) = (s>>5)*512 + (((s&31)>>3)*16+qs)*8 + ((s&31)&7)
    // B-read chunk c = 16B at table c + lane*8  -> conflict-free.
    __shared__ __align__(16) _Float16 h_tab[2][1024];

    const int tid  = threadIdx.x;
    const int wid  = tid >> 6;        // 0..6
    const int lane = tid & 63;
    const int qs   = lane & 15;       // sample / A-row-within-tile
    const int g2   = lane >> 4;       // K-group / C-row-group

    // ---------- prologue: zero h tables, stage x ----------
    {
        unsigned* hz = (unsigned*)&h_tab[0][0];
        for (int i = tid; i < 1024; i += THREADS) hz[i] = 0u;
        const float* xg = x + (size_t)blockIdx.x * SPB * TSTEPS;
        for (int i = tid; i < SPB * TSTEPS; i += THREADS)
            x_lds[(i >> 8) * XSTRIDE + (i & 255)] = xg[i];
    }

    // ---------- A fragments: 2 tiles per wave, gate-scaled fp16 ----------
    // tile ti: A-row qs -> unit uA = 8*wid + 4*ti + (qs>>2), gate q = qs&3 (i,f,g,o)
    // K element (kh,r): slot s = kh*32 + g2*8 + r holds unit un(s)
    // gate scale: i,f,o rows * -log2e ; g row * 2*log2e (exp2-native gates)
    half8 Ah[2][2];
    {
        const int q    = qs & 3;
        const float sc = (q == 2) ? 2.0f * L2E : -L2E;
#pragma unroll
        for (int ti = 0; ti < 2; ++ti) {
            const int uA  = 8 * wid + 4 * ti + (qs >> 2);
            const bool vr = (uA < HID);
            const int orow = q * HID + (vr ? uA : 0);
#pragma unroll
            for (int kh = 0; kh < 2; ++kh) {
#pragma unroll
                for (int r = 0; r < 8; ++r) {
                    const int s  = kh * 32 + g2 * 8 + r;
                    const int un = 8 * (s >> 3) + 4 * (s & 1) + ((s >> 1) & 3);
                    float v = 0.0f;
                    if (vr && un < HID) v = sc * W_hh[orow * HID + un];
                    Ah[ti][kh][r] = (_Float16)v;
                }
            }
        }
    }

    // per-lane cells: tile ti -> unit uC = 8*wid + 4*ti + g2, sample qs
    float wihc[2][4], bsumc[2][4];
    bool cv[2];
    _Float16* wp0[2];
#pragma unroll
    for (int ti = 0; ti < 2; ++ti) {
        const int uC = 8 * wid + 4 * ti + g2;
        cv[ti] = (uC < HID);
#pragma unroll
        for (int reg = 0; reg < 4; ++reg) {
            const float sc = (reg == 2) ? 2.0f * L2E : -L2E;
            const int orow = reg * HID + (cv[ti] ? uC : 0);
            wihc[ti][reg]  = sc * W_ih[orow];
            bsumc[ti][reg] = sc * (b_ih[orow] + b_hh[orow]);
        }
        const int s_w = slot_of_unit(cv[ti] ? uC : 0);
        const int p_w = s_w & 31;
        wp0[ti] = &h_tab[0][(s_w >> 5) * 512 + ((p_w >> 3) * 16 + qs) * 8 + (p_w & 7)];
    }

    __syncthreads();

    float cst0 = 0.0f, cst1 = 0.0f;
    half8 bh0, bh1;
    auto loadB = [&](int buf) {
        const _Float16* bp_ = &h_tab[buf][0] + lane * 8;
        bh0 = *(const half8*)(bp_);
        bh1 = *(const half8*)(bp_ + 512);
    };

    loadB(1);   // h(-1) = 0 from zeroed buf1

    const float* xrow = &x_lds[qs * XSTRIDE];

#pragma unroll 1
    for (int t4 = 0; t4 < TSTEPS; t4 += 4) {
        const float4 xq = *(const float4*)(xrow + t4);   // 4 timesteps of x, 16B-aligned
#pragma unroll
        for (int k = 0; k < 4; ++k) {
            const float xt = (k == 0) ? xq.x : (k == 1) ? xq.y : (k == 2) ? xq.z : xq.w;
            // acc init carries exact fp32 (scaled) bias + W_ih*x_t
            f32x4 acc0, acc1;
#pragma unroll
            for (int reg = 0; reg < 4; ++reg) {
                acc0[reg] = fmaf(wihc[0][reg], xt, bsumc[0][reg]);
                acc1[reg] = fmaf(wihc[1][reg], xt, bsumc[1][reg]);
            }
            acc0 = MF16(Ah[0][0], bh0, acc0);
            acc1 = MF16(Ah[1][0], bh0, acc1);
            acc0 = MF16(Ah[0][1], bh1, acc0);
            acc1 = MF16(Ah[1][1], bh1, acc1);

            // gates, cell 0
            const float i0 = sig2(acc0[0]);
            const float f0 = sig2(acc0[1]);
            const float g0 = 1.0f - 2.0f * sig2(acc0[2]);
            const float o0 = sig2(acc0[3]);
            cst0 = fmaf(f0, cst0, i0 * g0);
            const float h0 = o0 * fast_tanh(cst0);
            // gates, cell 1
            const float i1 = sig2(acc1[0]);
            const float f1 = sig2(acc1[1]);
            const float g1 = 1.0f - 2.0f * sig2(acc1[2]);
            const float o1 = sig2(acc1[3]);
            cst1 = fmaf(f1, cst1, i1 * g1);
            const float h1 = o1 * fast_tanh(cst1);

            const int boff = (k & 1) * 1024;   // static per unrolled k
            if (cv[0]) wp0[0][boff] = (_Float16)h0;
            if (cv[1]) wp0[1][boff] = (_Float16)h1;
            __syncthreads();
            loadB(k & 1);                      // h(t) for next step
        }
    }

    // ---------- epilogue: angles + 4-qubit circuit, 4 samples per wave (waves 0-3) ----------
    if (wid < 4) {
        const int sm  = 4 * wid + (lane >> 4);   // 0..15
        const int ql  = lane & 15;
        const int grp = lane & 48;

        const _Float16* t1 = &h_tab[1][0];   // h(255) lives in buf1
        float ang0 = bp[0], ang1 = bp[1], ang2 = bp[2], ang3 = bp[3];
#pragma unroll
        for (int kk = 0; kk < HID; ++kk) {
            const int s   = slot_of_unit(kk);
            const int p   = s & 31;
            const int idx = (s >> 5) * 512 + ((p >> 3) * 16 + sm) * 8 + (p & 7);
            const float hk = (float)t1[idx];
            ang0 = fmaf(Wp[0 * HID + kk], hk, ang0);
            ang1 = fmaf(Wp[1 * HID + kk], hk, ang1);
            ang2 = fmaf(Wp[2 * HID + kk], hk, ang2);
            ang3 = fmaf(Wp[3 * HID + kk], hk, ang3);
        }
        float ang[4];
        ang[0] = fast_tanh(ang0) * 1.57079632679489662f;
        ang[1] = fast_tanh(ang1) * 1.57079632679489662f;
        ang[2] = fast_tanh(ang2) * 1.57079632679489662f;
        ang[3] = fast_tanh(ang3) * 1.57079632679489662f;

        float ar = (ql == 0) ? 1.0f : 0.0f;
        float ai = 0.0f;

        // RX embedding
#pragma unroll
        for (int wq = 0; wq < 4; ++wq) {
            const int mask = 8 >> wq;
            float s_, c_;
            __sincosf(0.5f * ang[wq], &s_, &c_);
            const float pr = __shfl_xor(ar, mask);
            const float pi = __shfl_xor(ai, mask);
            const float nr = c_ * ar + s_ * pi;
            const float ni = c_ * ai - s_ * pr;
            ar = nr; ai = ni;
        }
        // StronglyEntanglingLayers
#pragma unroll
        for (int l = 0; l < 2; ++l) {
#pragma unroll
            for (int wq = 0; wq < 4; ++wq) {
                const float phi = qw[(l * 4 + wq) * 3 + 0];
                const float th  = qw[(l * 4 + wq) * 3 + 1];
                const float om  = qw[(l * 4 + wq) * 3 + 2];
                float st_, ct_, sa, ca, sb, cb;
                __sincosf(0.5f * th, &st_, &ct_);
                __sincosf(0.5f * (phi + om), &sa, &ca);
                __sincosf(0.5f * (phi - om), &sb, &cb);
                const int mask = 8 >> wq;
                const bool bit = (ql & mask) != 0;
                const float dr  = ca * ct_;
                const float di  = (bit ? sa : -sa) * ct_;
                const float orr = (bit ? cb : -cb) * st_;
                const float oi  = -sb * st_;
                const float pr = __shfl_xor(ar, mask);
                const float pi = __shfl_xor(ai, mask);
                const float nr = dr * ar - di * ai + orr * pr - oi * pi;
                const float ni = dr * ai + di * ar + orr * pi + oi * pr;
                ar = nr; ai = ni;
            }
            const int r = (l % 3) + 1;
#pragma unroll
            for (int wq = 0; wq < 4; ++wq) {
                const int mc  = 8 >> wq;
                const int mt  = 8 >> ((wq + r) % 4);
                const int src = (ql & mc) ? (ql ^ mt) : ql;
                ar = __shfl(ar, grp | src);
                ai = __shfl(ai, grp | src);
            }
        }
        const float prob = ar * ar + ai * ai;
        float coeff = 0.0f;
#pragma unroll
        for (int wq = 0; wq < 4; ++wq) {
            const float sgn = (ql & (8 >> wq)) ? -1.0f : 1.0f;
            coeff = fmaf(sgn, Wo[wq], coeff);
        }
        float v = prob * coeff;
        v += __shfl_xor(v, 1);
        v += __shfl_xor(v, 2);
        v += __shfl_xor(v, 4);
        v += __shfl_xor(v, 8);
        if (ql == 0) out[blockIdx.x * SPB + sm] = v + bo[0];
    }
}

extern "C" void kernel_launch(void* const* d_in, const int* in_sizes, int n_in,
                              void* d_out, int out_size, void* d_ws, size_t ws_size,
                              hipStream_t stream) {
    const float* x    = (const float*)d_in[0];
    const float* W_ih = (const float*)d_in[1];
    const float* W_hh = (const float*)d_in[2];
    const float* b_ih = (const float*)d_in[3];
    const float* b_hh = (const float*)d_in[4];
    const float* Wp   = (const float*)d_in[5];
    const float* bp   = (const float*)d_in[6];
    const float* qw   = (const float*)d_in[7];
    const float* Wo   = (const float*)d_in[8];
    const float* bo   = (const float*)d_in[9];
    float* out = (float*)d_out;

    const int B = in_sizes[0] / TSTEPS;
    hybrid_lstm_2t<<<B / SPB, THREADS, 0, stream>>>(x, W_ih, W_hh, b_ih, b_hh,
                                                    Wp, bp, qw, Wo, bo, out);
}